// Round 20
// baseline (65.035 us; speedup 1.0000x reference)
//
#include <hip/hip_runtime.h>
#include <hip/hip_bf16.h>

#define DEV static __device__ __forceinline__
#define AS1 __attribute__((address_space(1)))
#define AS3 __attribute__((address_space(3)))

typedef __attribute__((ext_vector_type(8))) short bf16x8;
typedef __attribute__((ext_vector_type(4))) short bf16x4;
typedef __attribute__((ext_vector_type(4))) float f32x4;

constexpr int NB = 4;        // batches
constexpr int SS = 2048;     // seq
constexpr int EE = 1024;     // embed
constexpr int DD = 64;       // low-rank d
constexpr int MTOT = NB * SS;  // 8192 rows total

// Q is pre-scaled by 1/sqrt(D) * log2(e) so softmax runs in exp2 domain.
#define QSCALE (0.125f * 1.44269504088896340736f)

DEV short f2bf(float f) {
    union { float f; unsigned u; } v; v.f = f;
    unsigned u = v.u;
    u += 0x7FFFu + ((u >> 16) & 1u);   // RNE
    return (short)(u >> 16);
}
DEV float bf2f(short h) {
    union { unsigned u; float f; } v; v.u = ((unsigned)(unsigned short)h) << 16;
    return v.f;
}
// packed bf16 pair via HW instruction (RNE, same as f2bf)
DEV unsigned pk2(float a, float b) {
    unsigned r;
    asm("v_cvt_pk_bf16_f32 %0, %1, %2" : "=v"(r) : "v"(a), "v"(b));
    return r;
}

DEV f32x4 mfma16(bf16x8 a, bf16x8 b, f32x4 c) {
    return __builtin_amdgcn_mfma_f32_16x16x32_bf16(a, b, c, 0, 0, 0);
}

DEV float redmax16(float v) {
    v = fmaxf(v, __shfl_xor(v, 1)); v = fmaxf(v, __shfl_xor(v, 2));
    v = fmaxf(v, __shfl_xor(v, 4)); v = fmaxf(v, __shfl_xor(v, 8));
    return v;
}
DEV float redsum16(float v) {
    v += __shfl_xor(v, 1); v += __shfl_xor(v, 2);
    v += __shfl_xor(v, 4); v += __shfl_xor(v, 8);
    return v;
}

// Frag layouts (all bf16, chunk = 64 lanes x 8 shorts = 1KB):
//  Qf/Kf  : [tile = globalrow/16][h2 = d/32]
//  VF     : [batch][c = k/32][n = d/16]
//  Tcat2  : [qtile][ks 0..4]  hi/lo slot map
//  Wcat2  : [vtile][ks 0..4]  (col 64 = bvL, 65.. = 0)
//  Wqb/Wkb/Wvb: sigma-permuted frags, linear in k-chunk it' = k/32:
//           offset it'*2048 + n*512 + lane*8.

// ---------------------------------------------------------------------------
// K0: fused weight prep: sigma-permuted frag-ordered Wq/Wk/Wv + Wcat2.
// grid 176, block 256.
// ---------------------------------------------------------------------------
__global__ __launch_bounds__(256) void k_prep(
    const float* __restrict__ Wq, const float* __restrict__ Wk,
    const float* __restrict__ Wv, const float* __restrict__ WvL,
    const float* __restrict__ bvL,
    short* __restrict__ Wqb, short* __restrict__ Wkb, short* __restrict__ Wvb,
    short* __restrict__ Wcat2)
{
    int g = blockIdx.x * 256 + threadIdx.x;
    if (g < 24576) {
        int mat = g >> 13;
        int c = g & 8191;
        int lane = c & 63;
        int fn = (c >> 6) & 3;
        int it = (c >> 8) & 7;
        int kq4 = c >> 11;
        int r = lane & 15, half = lane >> 4;
        int row = fn * 16 + r;
        int col = kq4 * 256 + it * 32 + half * 4;    // sigma
        const float* W = (mat == 0) ? Wq : ((mat == 1) ? Wk : Wv);
        short* O = (mat == 0) ? Wqb : ((mat == 1) ? Wkb : Wvb);
        float s = (mat == 0) ? QSCALE : 1.0f;
        const float* Wp = W + (size_t)row * EE + col;
        float4 u = *(const float4*)(Wp);
        float4 v = *(const float4*)(Wp + 16);
        bf16x8 o;
        unsigned* ou = (unsigned*)&o;
        ou[0] = pk2(u.x * s, u.y * s);
        ou[1] = pk2(u.z * s, u.w * s);
        ou[2] = pk2(v.x * s, v.y * s);
        ou[3] = pk2(v.z * s, v.w * s);
        *(bf16x8*)(O + (size_t)c * 8) = o;
    } else {
        int i2 = g - 24576;                  // 0..20479
        int lane = i2 & 63;
        int ks = (i2 >> 6) % 5;
        int vt = i2 / 320;
        int r = lane & 15, h = lane >> 4;
        int v = vt * 16 + r;
        bf16x8 o;
        #pragma unroll
        for (int j = 0; j < 8; ++j) {
            int c = ks * 16 + (h & 1) * 8 + j;
            float val = (c < 64) ? WvL[(size_t)v * DD + c] : ((c == 64) ? bvL[v] : 0.f);
            o[j] = f2bf(val);
        }
        *(bf16x8*)(Wcat2 + ((size_t)(vt * 5 + ks) * 64 + lane) * 8) = o;
    }
}

// ---------------------------------------------------------------------------
// K1 v7: projections with BLOCK-SHARED W staged in LDS. Block = 64 rows,
// 8 waves = 4 row-groups x 2-way split-K (512 each). Per step s: stage next
// W chunks (both K-halves) via global_load_lds (dbuf), A dbuf'd in regs,
// MFMA from LDS frags. 2-way LDS reduce (aliases stage buf), then frag
// emissions. W L2 traffic 4x lower than per-16-row blocks.
// grid (128, 2), block 512.
// ---------------------------------------------------------------------------
#define PJ_STAGE(buf, s) {                                                     \
    const short* s1_ = wA + ((size_t)(khT * 16 + (s)) * 2048) + t2 * 8;        \
    __builtin_amdgcn_global_load_lds((const AS1 void*)s1_,                     \
        (AS3 void*)(&wst[buf][wldsb]), 16, 0, 0);                              \
    if (!isQ) {                                                                \
        const short* s2_ = Wvb + ((size_t)(khT * 16 + (s)) * 2048) + t2 * 8;   \
        __builtin_amdgcn_global_load_lds((const AS1 void*)s2_,                 \
            (AS3 void*)(&wst[buf][wldsb + 2048]), 16, 0, 0);                   \
    } }

__global__ __launch_bounds__(512) void k_proj(
    const float* __restrict__ x, const float* __restrict__ y,
    const short* __restrict__ Wqb, const short* __restrict__ Wkb,
    const short* __restrict__ Wvb,
    const float* __restrict__ bq, const float* __restrict__ bk,
    const float* __restrict__ bv,
    short* __restrict__ Qf, short* __restrict__ Kf, short* __restrict__ VF)
{
    const int tid = threadIdx.x, wave = tid >> 6, lane = tid & 63;
    const int r = lane & 15, half = lane >> 4;
    const int rb = blockIdx.x * 64;
    const bool isQ = (blockIdx.y == 0);
    const float* src = isQ ? x : y;
    const short* wA = isQ ? Wqb : Wkb;
    const int rg = wave & 3, kh = wave >> 2;

    // stage thread-mapping (per-thread global src, wave-uniform LDS dest)
    const int khT = wave >> 2;                 // which K-half this wave stages
    const int t2 = tid & 255;                  // lane within the half's 4KB
    const int wldsb = khT * 4096 + (wave & 3) * 512;

    __shared__ __align__(16) short wst[2][8192];   // 2 x 16KB: [kh][K|V][2048]
    __shared__ float tl[64][68];                   // transpose tile (17.4KB)

    f32x4 accA[4] = {}, accB[4] = {};
    const float* arow = src + (size_t)(rb + rg * 16 + r) * EE + kh * 512 + half * 4;

    PJ_STAGE(0, 0)
    __syncthreads();

    float4 a0c = *(const float4*)(arow);
    float4 a1c = *(const float4*)(arow + 16);
    float4 a0n, a1n;

    int buf = 0;
    #pragma unroll 4
    for (int s = 0; s < 16; ++s) {
        if (s + 1 < 16) {
            PJ_STAGE(buf ^ 1, s + 1)
            a0n = *(const float4*)(arow + (s + 1) * 32);
            a1n = *(const float4*)(arow + (s + 1) * 32 + 16);
        }
        bf16x8 a;
        unsigned* au = (unsigned*)&a;
        au[0] = pk2(a0c.x, a0c.y);
        au[1] = pk2(a0c.z, a0c.w);
        au[2] = pk2(a1c.x, a1c.y);
        au[3] = pk2(a1c.z, a1c.w);
        const short* wsl = &wst[buf][kh * 4096];
        #pragma unroll
        for (int n = 0; n < 4; ++n) {
            bf16x8 bw = *(const bf16x8*)(wsl + n * 512 + lane * 8);
            accA[n] = mfma16(a, bw, accA[n]);
        }
        if (!isQ) {
            #pragma unroll
            for (int n = 0; n < 4; ++n) {
                bf16x8 bv_ = *(const bf16x8*)(wsl + 2048 + n * 512 + lane * 8);
                accB[n] = mfma16(a, bv_, accB[n]);
            }
        }
        a0c = a0n; a1c = a1n;
        __syncthreads();
        buf ^= 1;
    }

    // 2-way split-K reduce: kh=1 waves publish, kh=0 waves absorb.
    f32x4* red = (f32x4*)&wst[0][0];   // [rg][ms][n][64] = 32KB (aliases stage)
    if (kh == 1) {
        #pragma unroll
        for (int n = 0; n < 4; ++n) red[((rg * 2 + 0) * 4 + n) * 64 + lane] = accA[n];
        if (!isQ) {
            #pragma unroll
            for (int n = 0; n < 4; ++n) red[((rg * 2 + 1) * 4 + n) * 64 + lane] = accB[n];
        }
    }
    __syncthreads();
    if (kh == 0) {
        #pragma unroll
        for (int n = 0; n < 4; ++n) accA[n] += red[((rg * 2 + 0) * 4 + n) * 64 + lane];
        if (!isQ) {
            #pragma unroll
            for (int n = 0; n < 4; ++n) accB[n] += red[((rg * 2 + 1) * 4 + n) * 64 + lane];
        }
    }
    __syncthreads();

    // ---- emit Qf/Kf: bias + transpose tile + frag write ----
    if (kh == 0) {
        #pragma unroll
        for (int n = 0; n < 4; ++n) {
            int col = n * 16 + r;
            float bias = isQ ? (bq[col] * QSCALE) : bk[col];
            #pragma unroll
            for (int ri = 0; ri < 4; ++ri)
                tl[rg * 16 + half * 4 + ri][col] = accA[n][ri] + bias;
        }
    }
    __syncthreads();
    {
        int tt = tid >> 7;                 // 0..3 (16-row tile)
        int h2 = (tid >> 6) & 1;
        int l2 = tid & 63, r2 = l2 & 15, hh = l2 >> 4;
        const float* base = &tl[tt * 16 + r2][h2 * 32 + hh * 8];
        bf16x8 o;
        unsigned* ou = (unsigned*)&o;
        #pragma unroll
        for (int jj = 0; jj < 4; ++jj)
            ou[jj] = pk2(base[2 * jj], base[2 * jj + 1]);
        short* dst = (isQ ? Qf : Kf) + ((size_t)(rb / 16 + tt) * 2 + h2) * 512 + l2 * 8;
        *(bf16x8*)dst = o;
    }

    if (!isQ) {
        __syncthreads();
        if (kh == 0) {
            #pragma unroll
            for (int n = 0; n < 4; ++n) {
                int col = n * 16 + r;
                float bias = bv[col];
                #pragma unroll
                for (int ri = 0; ri < 4; ++ri)
                    tl[rg * 16 + half * 4 + ri][col] = accB[n][ri] + bias;
            }
        }
        __syncthreads();
        {
            int cgl = tid >> 8;            // 0..1 (32-row group)
            int nn = (tid >> 6) & 3;
            int l2 = tid & 63, r2 = l2 & 15, h2q = l2 >> 4;
            bf16x8 o;
            unsigned* ou = (unsigned*)&o;
            #pragma unroll
            for (int jj = 0; jj < 4; ++jj)
                ou[jj] = pk2(tl[cgl * 32 + h2q * 8 + 2 * jj][nn * 16 + r2],
                             tl[cgl * 32 + h2q * 8 + 2 * jj + 1][nn * 16 + r2]);
            int batch = rb >> 11;
            int cg2 = ((rb & 2047) >> 5) + cgl;
            *(bf16x8*)(VF + (((size_t)batch * 64 + cg2) * 4 + nn) * 512 + l2 * 8) = o;
        }
    }
}

// ---------------------------------------------------------------------------
// K2: column-softmax STATS only: M[k], 1/L[k]. grid (128, NB), block 512.
// ---------------------------------------------------------------------------
__global__ __launch_bounds__(512) void k_stats(
    const short* __restrict__ Qf, const short* __restrict__ Kf,
    float* __restrict__ Ml, float* __restrict__ Rl)
{
    const int tid = threadIdx.x, wave = tid >> 6, lane = tid & 63;
    const int r = lane & 15, half = lane >> 4;
    const int batch = blockIdx.y;
    const int kb = blockIdx.x * 16;

    __shared__ float smax[8][16], ssum[8][16];

    const short* kfp = Kf + ((size_t)(batch * 128 + (kb >> 4)) * 2) * 512 + lane * 8;
    bf16x8 kf0 = *(const bf16x8*)kfp;
    bf16x8 kf1 = *(const bf16x8*)(kfp + 512);

    const int qt0 = batch * 128 + wave * 16;
    f32x4 s[16];
    #pragma unroll
    for (int t = 0; t < 16; ++t) {
        const short* qp = Qf + ((size_t)(qt0 + t) * 2) * 512 + lane * 8;
        bf16x8 a0 = *(const bf16x8*)qp;
        bf16x8 a1 = *(const bf16x8*)(qp + 512);
        f32x4 c = {};
        c = mfma16(kf0, a0, c);
        c = mfma16(kf1, a1, c);
        s[t] = c;
    }
    f32x4 m4 = s[0];
    #pragma unroll
    for (int t = 1; t < 16; ++t) {
        #pragma unroll
        for (int ri = 0; ri < 4; ++ri) m4[ri] = fmaxf(m4[ri], s[t][ri]);
    }
    #pragma unroll
    for (int ri = 0; ri < 4; ++ri) m4[ri] = redmax16(m4[ri]);
    if (r == 0) {
        #pragma unroll
        for (int ri = 0; ri < 4; ++ri) smax[wave][half * 4 + ri] = m4[ri];
    }
    __syncthreads();
    f32x4 M;
    #pragma unroll
    for (int ri = 0; ri < 4; ++ri) {
        float v = smax[0][half * 4 + ri];
        #pragma unroll
        for (int w = 1; w < 8; ++w) v = fmaxf(v, smax[w][half * 4 + ri]);
        M[ri] = v;
    }
    f32x4 l4 = {};
    #pragma unroll
    for (int t = 0; t < 16; ++t)
        #pragma unroll
        for (int ri = 0; ri < 4; ++ri) l4[ri] += exp2f(s[t][ri] - M[ri]);
    #pragma unroll
    for (int ri = 0; ri < 4; ++ri) l4[ri] = redsum16(l4[ri]);
    if (r == 0) {
        #pragma unroll
        for (int ri = 0; ri < 4; ++ri) ssum[wave][half * 4 + ri] = l4[ri];
    }
    __syncthreads();
    if (wave == 0 && r == 0) {
        f32x4 rl;
        #pragma unroll
        for (int ri = 0; ri < 4; ++ri) {
            float v = 0.f;
            #pragma unroll
            for (int w = 0; w < 8; ++w) v += ssum[w][half * 4 + ri];
            rl[ri] = 1.0f / v;
        }
        *(f32x4*)(Ml + (size_t)batch * SS + kb + half * 4) = M;
        *(f32x4*)(Rl + (size_t)batch * SS + kb + half * 4) = rl;
    }
}

// ---------------------------------------------------------------------------
// K3: fused PV, flash-style — P never hits HBM. Block = 16 q-rows; 8 waves
// k-split 256 each; setprio around MFMA. grid 512 (XCD-chunked), block 512.
// ---------------------------------------------------------------------------
__global__ __launch_bounds__(512) void k_pvfuse(
    const short* __restrict__ Qf, const short* __restrict__ Kf,
    const short* __restrict__ VF,
    const float* __restrict__ Ml, const float* __restrict__ Rl,
    short* __restrict__ Tcat2)
{
    const int tid = threadIdx.x, wave = tid >> 6, lane = tid & 63;
    const int r = lane & 15, half = lane >> 4;
    const int bid = blockIdx.x;
    const int qt = (bid & 7) * 64 + (bid >> 3);   // XCD-chunked; 0..511
    const int batch = qt >> 7;
    const int kbase = wave * 256;

    __shared__ short pl[8][16][40];               // per-wave P bounce
    __shared__ f32x4 red2[8][5][64];
    __shared__ float tl2[16][84];

    const short* qp = Qf + (size_t)qt * 2 * 512 + lane * 8;
    bf16x8 qf0 = *(const bf16x8*)qp;
    bf16x8 qf1 = *(const bf16x8*)(qp + 512);
    bf16x8 ones;
    #pragma unroll
    for (int j = 0; j < 8; ++j) ones[j] = (r == 0) ? (short)0x3F80 : (short)0;

    const float* mlb = Ml + (size_t)batch * SS;
    const float* rlb = Rl + (size_t)batch * SS;
    const short* kfb = Kf + (size_t)batch * 128 * 1024;
    const short* vfb = VF + (size_t)batch * 64 * 4 * 512;

    f32x4 acc[5] = {};

    #pragma unroll 2
    for (int st = 0; st < 8; ++st) {
        const int kt = kbase + st * 32;
        const short* kp = kfb + (size_t)(kt >> 4) * 1024 + lane * 8;
        bf16x8 k00 = *(const bf16x8*)kp;
        bf16x8 k01 = *(const bf16x8*)(kp + 512);
        bf16x8 k10 = *(const bf16x8*)(kp + 1024);
        bf16x8 k11 = *(const bf16x8*)(kp + 1536);
        f32x4 s0 = {}, s1 = {};
        __builtin_amdgcn_s_setprio(1);
        s0 = mfma16(k00, qf0, s0); s0 = mfma16(k01, qf1, s0);
        s1 = mfma16(k10, qf0, s1); s1 = mfma16(k11, qf1, s1);
        __builtin_amdgcn_s_setprio(0);
        f32x4 m0 = *(const f32x4*)(mlb + kt + half * 4);
        f32x4 r0 = *(const f32x4*)(rlb + kt + half * 4);
        f32x4 m1 = *(const f32x4*)(mlb + kt + 16 + half * 4);
        f32x4 r1 = *(const f32x4*)(rlb + kt + 16 + half * 4);
        f32x4 p0, p1;
        #pragma unroll
        for (int ri = 0; ri < 4; ++ri) {
            p0[ri] = exp2f(s0[ri] - m0[ri]) * r0[ri];
            p1[ri] = exp2f(s1[ri] - m1[ri]) * r1[ri];
        }
        uint2 u0, u1;
        u0.x = pk2(p0[0], p0[1]); u0.y = pk2(p0[2], p0[3]);
        u1.x = pk2(p1[0], p1[1]); u1.y = pk2(p1[2], p1[3]);
        *(uint2*)&pl[wave][r][4 * half] = u0;
        *(uint2*)&pl[wave][r][16 + 4 * half] = u1;
        bf16x8 af = *(const bf16x8*)&pl[wave][r][half * 8];
        __builtin_amdgcn_s_setprio(1);
        #pragma unroll
        for (int nn = 0; nn < 4; ++nn) {
            bf16x8 vf = *(const bf16x8*)(vfb + ((size_t)(kt >> 5) * 4 + nn) * 512 + lane * 8);
            acc[nn] = mfma16(af, vf, acc[nn]);
        }
        acc[4] = mfma16(af, ones, acc[4]);
        __builtin_amdgcn_s_setprio(0);
    }

    #pragma unroll
    for (int nn = 0; nn < 5; ++nn) red2[wave][nn][lane] = acc[nn];
    __syncthreads();
    if (wave < 5) {
        int nn = wave;
        f32x4 v = red2[0][nn][lane];
        #pragma unroll
        for (int w = 1; w < 8; ++w) v += red2[w][nn][lane];
        #pragma unroll
        for (int ri = 0; ri < 4; ++ri) tl2[half * 4 + ri][nn * 16 + r] = v[ri];
    }
    __syncthreads();
    if (tid < 320) {
        int ks = tid >> 6;
        int l2 = tid & 63;
        int r2 = l2 & 15, h2 = l2 >> 4;
        bf16x8 o;
        #pragma unroll
        for (int j = 0; j < 8; ++j) {
            float v = tl2[r2][ks * 16 + (h2 & 1) * 8 + j];
            short hi = f2bf(v);
            o[j] = (h2 < 2) ? hi : f2bf(v - bf2f(hi));
        }
        *(bf16x8*)(Tcat2 + (((size_t)qt * 5 + ks) * 64 + l2) * 8) = o;
    }
}

// ---------------------------------------------------------------------------
// K4: GEMM2 — out = Tcat2 (.) Wcat2 over 5 frag-chunks (hi/lo interleave).
// grid 512 flat, block 256. Write-bound.
// ---------------------------------------------------------------------------
__global__ __launch_bounds__(256) void k_gemm2(
    const short* __restrict__ Tcat2, const short* __restrict__ Wcat2,
    float* __restrict__ out)
{
    const int tid = threadIdx.x, wave = tid >> 6, lane = tid & 63;
    const int r = lane & 15, half = lane >> 4;
    const int wm = wave >> 1, wn = wave & 1;
    const int bid = blockIdx.x;
    const int w = (bid & 7) * 64 + (bid >> 3);
    const int qB = (w >> 3) * 128;
    const int vB = (w & 7) * 128;
    const int tA0 = qB / 16 + wm * 4;
    const int vt0 = vB / 16 + wn * 4;

    f32x4 acc[4][4] = {};
    #pragma unroll
    for (int ks = 0; ks < 5; ++ks) {
        bf16x8 a[4], b[4];
        #pragma unroll
        for (int i = 0; i < 4; ++i) {
            a[i] = *(const bf16x8*)(Tcat2 + ((size_t)(tA0 + i) * 5 + ks) * 512 + lane * 8);
            b[i] = *(const bf16x8*)(Wcat2 + ((size_t)(vt0 + i) * 5 + ks) * 512 + lane * 8);
        }
        #pragma unroll
        for (int mi = 0; mi < 4; ++mi)
            #pragma unroll
            for (int ni = 0; ni < 4; ++ni)
                acc[mi][ni] = mfma16(a[mi], b[ni], acc[mi][ni]);
    }

    const int r4 = half * 4;
    #pragma unroll
    for (int mi = 0; mi < 4; ++mi)
        #pragma unroll
        for (int ni = 0; ni < 4; ++ni)
            #pragma unroll
            for (int ri = 0; ri < 4; ++ri)
                out[(size_t)(qB + wm * 64 + mi * 16 + r4 + ri) * EE + vB + wn * 64 + ni * 16 + r] = acc[mi][ni][ri];
}

// ---------------------------------------------------------------------------
extern "C" void kernel_launch(void* const* d_in, const int* in_sizes, int n_in,
                              void* d_out, int out_size, void* d_ws, size_t ws_size,
                              hipStream_t stream) {
    (void)in_sizes; (void)n_in; (void)out_size; (void)ws_size;
    const float* x   = (const float*)d_in[0];
    const float* y   = (const float*)d_in[1];
    const float* Wq  = (const float*)d_in[2];
    const float* bq  = (const float*)d_in[3];
    const float* Wk  = (const float*)d_in[4];
    const float* bk  = (const float*)d_in[5];
    const float* WvR = (const float*)d_in[6];
    const float* bvR = (const float*)d_in[7];
    const float* WvL = (const float*)d_in[8];
    const float* bvL = (const float*)d_in[9];
    float* out = (float*)d_out;

    short* Qf    = (short*)d_ws;                      // 524288 sh
    short* Kf    = Qf    + (size_t)MTOT * DD;         // 524288
    short* VF    = Kf    + (size_t)MTOT * DD;         // 524288
    short* Tcat2 = VF    + (size_t)MTOT * DD;         // 1310720
    short* Wqb   = Tcat2 + (size_t)(MTOT / 16) * 5 * 512;   // 65536
    short* Wkb   = Wqb   + (size_t)DD * EE;
    short* Wvb   = Wkb   + (size_t)DD * EE;
    short* Wcat2 = Wvb   + (size_t)DD * EE;           // 163840
    float* Ml    = (float*)(Wcat2 + (size_t)64 * 5 * 512);  // 8192 f32
    float* Rl    = Ml + MTOT;

    k_prep<<<dim3(176), 256, 0, stream>>>(Wq, Wk, WvR, WvL, bvL, Wqb, Wkb, Wvb, Wcat2);
    k_proj<<<dim3(MTOT / 64, 2), 512, 0, stream>>>(x, y, Wqb, Wkb, Wvb, bq, bk, bvR, Qf, Kf, VF);
    k_stats<<<dim3(SS / 16, NB), 512, 0, stream>>>(Qf, Kf, Ml, Rl);
    k_pvfuse<<<dim3(512), 512, 0, stream>>>(Qf, Kf, VF, Ml, Rl, Tcat2);
    k_gemm2<<<dim3(512), 256, 0, stream>>>(Tcat2, Wcat2, out);
}

// Round 21
// 62.701 us; speedup vs baseline: 1.0372x; 1.0372x over previous
//
#include <hip/hip_runtime.h>
#include <hip/hip_bf16.h>

#define DEV static __device__ __forceinline__
#define AS1 __attribute__((address_space(1)))
#define AS3 __attribute__((address_space(3)))

typedef __attribute__((ext_vector_type(8))) short bf16x8;
typedef __attribute__((ext_vector_type(4))) short bf16x4;
typedef __attribute__((ext_vector_type(4))) float f32x4;

constexpr int NB = 4;        // batches
constexpr int SS = 2048;     // seq
constexpr int EE = 1024;     // embed
constexpr int DD = 64;       // low-rank d
constexpr int MTOT = NB * SS;  // 8192 rows total

// Q is pre-scaled by 1/sqrt(D) * log2(e) so softmax runs in exp2 domain.
#define QSCALE (0.125f * 1.44269504088896340736f)

DEV short f2bf(float f) {
    union { float f; unsigned u; } v; v.f = f;
    unsigned u = v.u;
    u += 0x7FFFu + ((u >> 16) & 1u);   // RNE
    return (short)(u >> 16);
}
DEV float bf2f(short h) {
    union { unsigned u; float f; } v; v.u = ((unsigned)(unsigned short)h) << 16;
    return v.f;
}
// packed bf16 pair via HW instruction (RNE, same as f2bf)
DEV unsigned pk2(float a, float b) {
    unsigned r;
    asm("v_cvt_pk_bf16_f32 %0, %1, %2" : "=v"(r) : "v"(a), "v"(b));
    return r;
}

DEV f32x4 mfma16(bf16x8 a, bf16x8 b, f32x4 c) {
    return __builtin_amdgcn_mfma_f32_16x16x32_bf16(a, b, c, 0, 0, 0);
}

DEV float redmax16(float v) {
    v = fmaxf(v, __shfl_xor(v, 1)); v = fmaxf(v, __shfl_xor(v, 2));
    v = fmaxf(v, __shfl_xor(v, 4)); v = fmaxf(v, __shfl_xor(v, 8));
    return v;
}
DEV float redsum16(float v) {
    v += __shfl_xor(v, 1); v += __shfl_xor(v, 2);
    v += __shfl_xor(v, 4); v += __shfl_xor(v, 8);
    return v;
}

// Frag layouts (all bf16, chunk = 64 lanes x 8 shorts = 1KB):
//  Qf/Kf  : [tile = globalrow/16][h2 = d/32]
//  VF     : [batch][c = k/32][n = d/16]
//  Tcat2  : [qtile][ks 0..4]  hi/lo slot map
//  Wcat2  : [vtile][ks 0..4]  (col 64 = bvL, 65.. = 0)
//  Wqb/Wkb/Wvb: sigma-PERMUTED frags matching k_proj's contiguous A-load.

// ---------------------------------------------------------------------------
// K0: fused weight prep: sigma-permuted frag-ordered Wq/Wk/Wv + Wcat2.
// grid 176, block 256.
// ---------------------------------------------------------------------------
__global__ __launch_bounds__(256) void k_prep(
    const float* __restrict__ Wq, const float* __restrict__ Wk,
    const float* __restrict__ Wv, const float* __restrict__ WvL,
    const float* __restrict__ bvL,
    short* __restrict__ Wqb, short* __restrict__ Wkb, short* __restrict__ Wvb,
    short* __restrict__ Wcat2)
{
    int g = blockIdx.x * 256 + threadIdx.x;
    if (g < 24576) {
        int mat = g >> 13;
        int c = g & 8191;
        int lane = c & 63;
        int fn = (c >> 6) & 3;
        int it = (c >> 8) & 7;
        int kq4 = c >> 11;
        int r = lane & 15, half = lane >> 4;
        int row = fn * 16 + r;
        int col = kq4 * 256 + it * 32 + half * 4;    // sigma
        const float* W = (mat == 0) ? Wq : ((mat == 1) ? Wk : Wv);
        short* O = (mat == 0) ? Wqb : ((mat == 1) ? Wkb : Wvb);
        float s = (mat == 0) ? QSCALE : 1.0f;
        const float* Wp = W + (size_t)row * EE + col;
        float4 u = *(const float4*)(Wp);
        float4 v = *(const float4*)(Wp + 16);
        bf16x8 o;
        unsigned* ou = (unsigned*)&o;
        ou[0] = pk2(u.x * s, u.y * s);
        ou[1] = pk2(u.z * s, u.w * s);
        ou[2] = pk2(v.x * s, v.y * s);
        ou[3] = pk2(v.z * s, v.w * s);
        *(bf16x8*)(O + (size_t)c * 8) = o;
    } else {
        int i2 = g - 24576;                  // 0..20479
        int lane = i2 & 63;
        int ks = (i2 >> 6) % 5;
        int vt = i2 / 320;
        int r = lane & 15, h = lane >> 4;
        int v = vt * 16 + r;
        bf16x8 o;
        #pragma unroll
        for (int j = 0; j < 8; ++j) {
            int c = ks * 16 + (h & 1) * 8 + j;
            float val = (c < 64) ? WvL[(size_t)v * DD + c] : ((c == 64) ? bvL[v] : 0.f);
            o[j] = f2bf(val);
        }
        *(bf16x8*)(Wcat2 + ((size_t)(vt * 5 + ks) * 64 + lane) * 8) = o;
    }
}

// ---------------------------------------------------------------------------
// K1 (R19 version — best measured): projections, split-K, sigma-permuted W;
// W-frags double-buffered one iteration ahead; A fully prefetched.
// grid (512, 2), block 256.
// ---------------------------------------------------------------------------
__global__ __launch_bounds__(256) void k_proj(
    const float* __restrict__ x, const float* __restrict__ y,
    const short* __restrict__ Wqb, const short* __restrict__ Wkb,
    const short* __restrict__ Wvb,
    const float* __restrict__ bq, const float* __restrict__ bk,
    const float* __restrict__ bv,
    short* __restrict__ Qf, short* __restrict__ Kf, short* __restrict__ VF)
{
    const int tid = threadIdx.x, wave = tid >> 6, lane = tid & 63;
    const int r = lane & 15, half = lane >> 4;
    const int rb = blockIdx.x * 16;
    const bool isQ = (blockIdx.y == 0);
    const float* src = isQ ? x : y;
    const short* wA = isQ ? Wqb : Wkb;
    const int kq = wave * 256;

    __shared__ f32x4 red[4][8][64];

    f32x4 accA[4] = {}, accB[4] = {};
    const float* arow = src + (size_t)(rb + r) * EE + kq + half * 4;  // sigma
    const short* wbase = wA + (size_t)wave * 16384 + lane * 8;
    const short* vbase = Wvb + (size_t)wave * 16384 + lane * 8;

    float4 af0[8], af1[8];
    #pragma unroll
    for (int it = 0; it < 8; ++it) {
        af0[it] = *(const float4*)(arow + it * 32);        // cols 4h+0..3
        af1[it] = *(const float4*)(arow + it * 32 + 16);   // cols 16+4h+0..3
    }

    // W double-buffer: preload it=0
    bf16x8 bwc[4], bvc[4], bwn[4], bvn[4];
    #pragma unroll
    for (int n = 0; n < 4; ++n) bwc[n] = *(const bf16x8*)(wbase + n * 512);
    if (!isQ) {
        #pragma unroll
        for (int n = 0; n < 4; ++n) bvc[n] = *(const bf16x8*)(vbase + n * 512);
    }

    #pragma unroll
    for (int it = 0; it < 8; ++it) {
        if (it < 7) {
            #pragma unroll
            for (int n = 0; n < 4; ++n)
                bwn[n] = *(const bf16x8*)(wbase + ((it + 1) * 4 + n) * 512);
            if (!isQ) {
                #pragma unroll
                for (int n = 0; n < 4; ++n)
                    bvn[n] = *(const bf16x8*)(vbase + ((it + 1) * 4 + n) * 512);
            }
        }
        bf16x8 a;
        unsigned* au = (unsigned*)&a;
        au[0] = pk2(af0[it].x, af0[it].y);
        au[1] = pk2(af0[it].z, af0[it].w);
        au[2] = pk2(af1[it].x, af1[it].y);
        au[3] = pk2(af1[it].z, af1[it].w);
        #pragma unroll
        for (int n = 0; n < 4; ++n)
            accA[n] = mfma16(a, bwc[n], accA[n]);
        if (!isQ) {
            #pragma unroll
            for (int n = 0; n < 4; ++n)
                accB[n] = mfma16(a, bvc[n], accB[n]);
        }
        #pragma unroll
        for (int n = 0; n < 4; ++n) bwc[n] = bwn[n];
        if (!isQ) {
            #pragma unroll
            for (int n = 0; n < 4; ++n) bvc[n] = bvn[n];
        }
    }

    #pragma unroll
    for (int n = 0; n < 4; ++n) red[wave][n][lane] = accA[n];
    if (!isQ) {
        #pragma unroll
        for (int n = 0; n < 4; ++n) red[wave][4 + n][lane] = accB[n];
    }
    __syncthreads();

    const int n = wave;
    const int col = n * 16 + r;
    f32x4 s = red[0][n][lane];
    #pragma unroll
    for (int w = 1; w < 4; ++w) s += red[w][n][lane];
    float biasA = isQ ? (bq[col] * QSCALE) : bk[col];
    f32x4 t = {};
    float biasB = 0.f;
    if (!isQ) {
        t = red[0][4 + n][lane];
        #pragma unroll
        for (int w = 1; w < 4; ++w) t += red[w][4 + n][lane];
        biasB = bv[col];
    }
    __syncthreads();                       // red consumed; alias as f32 tiles
    float* tlA = (float*)&red[0][0][0];    // [16][68]
    float* tlB = tlA + 16 * 68;            // [16][68]
    #pragma unroll
    for (int ri = 0; ri < 4; ++ri)
        tlA[(half * 4 + ri) * 68 + col] = s[ri] + biasA;
    if (!isQ) {
        #pragma unroll
        for (int ri = 0; ri < 4; ++ri)
            tlB[(half * 4 + ri) * 68 + col] = t[ri] + biasB;
    }
    __syncthreads();
    if (tid < 128) {
        int h2 = tid >> 6, l2 = tid & 63, r2 = l2 & 15, hh = l2 >> 4;
        const float* base = tlA + r2 * 68 + h2 * 32 + hh * 8;
        bf16x8 o;
        unsigned* ou = (unsigned*)&o;
        #pragma unroll
        for (int jj = 0; jj < 4; ++jj)
            ou[jj] = pk2(base[2 * jj], base[2 * jj + 1]);
        short* dst = (isQ ? Qf : Kf) + ((size_t)blockIdx.x * 2 + h2) * 512 + l2 * 8;
        *(bf16x8*)dst = o;
    } else if (!isQ) {
        int idx = tid - 128;                 // 0..127
        int nn = idx >> 5, sub = idx & 31;
        int r2 = sub & 15, su = sub >> 4;    // su in {0,1}
        int hbase = (rb & 16) ? 2 : 0;
        int lane2 = ((hbase + su) << 4) | r2;
        const float* base = tlB + (size_t)su * 8 * 68 + nn * 16 + r2;
        bf16x8 o;
        unsigned* ou = (unsigned*)&o;
        #pragma unroll
        for (int jj = 0; jj < 4; ++jj)
            ou[jj] = pk2(base[(2 * jj) * 68], base[(2 * jj + 1) * 68]);
        int batch = rb >> 11;
        int cg2 = (rb & 2047) >> 5;
        *(bf16x8*)(VF + (((size_t)batch * 64 + cg2) * 4 + nn) * 512 + lane2 * 8) = o;
    }
}

// ---------------------------------------------------------------------------
// K2 v2: column-softmax STATS, 32 k-cols per block (halves Q re-reads: each
// wave's Q-frag loads amortize over 2 K-tiles). grid (64, NB), block 512.
// ---------------------------------------------------------------------------
__global__ __launch_bounds__(512) void k_stats(
    const short* __restrict__ Qf, const short* __restrict__ Kf,
    float* __restrict__ Ml, float* __restrict__ Rl)
{
    const int tid = threadIdx.x, wave = tid >> 6, lane = tid & 63;
    const int r = lane & 15, half = lane >> 4;
    const int batch = blockIdx.y;
    const int kb = blockIdx.x * 32;

    __shared__ float smax[8][32], ssum[8][32];

    const short* kfp = Kf + ((size_t)(batch * 128 + (kb >> 4)) * 2) * 512 + lane * 8;
    bf16x8 kf0 = *(const bf16x8*)kfp;
    bf16x8 kf1 = *(const bf16x8*)(kfp + 512);
    bf16x8 kf2 = *(const bf16x8*)(kfp + 1024);
    bf16x8 kf3 = *(const bf16x8*)(kfp + 1536);

    const int qt0 = batch * 128 + wave * 16;
    f32x4 sa[16], sb[16];
    #pragma unroll
    for (int t = 0; t < 16; ++t) {
        const short* qp = Qf + ((size_t)(qt0 + t) * 2) * 512 + lane * 8;
        bf16x8 a0 = *(const bf16x8*)qp;
        bf16x8 a1 = *(const bf16x8*)(qp + 512);
        f32x4 ca = {}, cb = {};
        ca = mfma16(kf0, a0, ca);
        ca = mfma16(kf1, a1, ca);
        cb = mfma16(kf2, a0, cb);
        cb = mfma16(kf3, a1, cb);
        sa[t] = ca;
        sb[t] = cb;
    }
    f32x4 m4a = sa[0], m4b = sb[0];
    #pragma unroll
    for (int t = 1; t < 16; ++t) {
        #pragma unroll
        for (int ri = 0; ri < 4; ++ri) {
            m4a[ri] = fmaxf(m4a[ri], sa[t][ri]);
            m4b[ri] = fmaxf(m4b[ri], sb[t][ri]);
        }
    }
    #pragma unroll
    for (int ri = 0; ri < 4; ++ri) {
        m4a[ri] = redmax16(m4a[ri]);
        m4b[ri] = redmax16(m4b[ri]);
    }
    if (r == 0) {
        #pragma unroll
        for (int ri = 0; ri < 4; ++ri) {
            smax[wave][half * 4 + ri] = m4a[ri];
            smax[wave][16 + half * 4 + ri] = m4b[ri];
        }
    }
    __syncthreads();
    f32x4 Ma, Mb;
    #pragma unroll
    for (int ri = 0; ri < 4; ++ri) {
        float va = smax[0][half * 4 + ri];
        float vb = smax[0][16 + half * 4 + ri];
        #pragma unroll
        for (int w = 1; w < 8; ++w) {
            va = fmaxf(va, smax[w][half * 4 + ri]);
            vb = fmaxf(vb, smax[w][16 + half * 4 + ri]);
        }
        Ma[ri] = va; Mb[ri] = vb;
    }
    f32x4 l4a = {}, l4b = {};
    #pragma unroll
    for (int t = 0; t < 16; ++t) {
        #pragma unroll
        for (int ri = 0; ri < 4; ++ri) {
            l4a[ri] += exp2f(sa[t][ri] - Ma[ri]);
            l4b[ri] += exp2f(sb[t][ri] - Mb[ri]);
        }
    }
    #pragma unroll
    for (int ri = 0; ri < 4; ++ri) {
        l4a[ri] = redsum16(l4a[ri]);
        l4b[ri] = redsum16(l4b[ri]);
    }
    if (r == 0) {
        #pragma unroll
        for (int ri = 0; ri < 4; ++ri) {
            ssum[wave][half * 4 + ri] = l4a[ri];
            ssum[wave][16 + half * 4 + ri] = l4b[ri];
        }
    }
    __syncthreads();
    if (wave == 0 && r == 0) {
        f32x4 rla, rlb;
        #pragma unroll
        for (int ri = 0; ri < 4; ++ri) {
            float va = 0.f, vb = 0.f;
            #pragma unroll
            for (int w = 0; w < 8; ++w) {
                va += ssum[w][half * 4 + ri];
                vb += ssum[w][16 + half * 4 + ri];
            }
            rla[ri] = 1.0f / va;
            rlb[ri] = 1.0f / vb;
        }
        *(f32x4*)(Ml + (size_t)batch * SS + kb + half * 4) = Ma;
        *(f32x4*)(Ml + (size_t)batch * SS + kb + 16 + half * 4) = Mb;
        *(f32x4*)(Rl + (size_t)batch * SS + kb + half * 4) = rla;
        *(f32x4*)(Rl + (size_t)batch * SS + kb + 16 + half * 4) = rlb;
    }
}

// ---------------------------------------------------------------------------
// K3: fused PV, flash-style — P never hits HBM. Block = 16 q-rows; 8 waves
// k-split 256 each; setprio around MFMA. grid 512 (XCD-chunked), block 512.
// ---------------------------------------------------------------------------
__global__ __launch_bounds__(512) void k_pvfuse(
    const short* __restrict__ Qf, const short* __restrict__ Kf,
    const short* __restrict__ VF,
    const float* __restrict__ Ml, const float* __restrict__ Rl,
    short* __restrict__ Tcat2)
{
    const int tid = threadIdx.x, wave = tid >> 6, lane = tid & 63;
    const int r = lane & 15, half = lane >> 4;
    const int bid = blockIdx.x;
    const int qt = (bid & 7) * 64 + (bid >> 3);   // XCD-chunked; 0..511
    const int batch = qt >> 7;
    const int kbase = wave * 256;

    __shared__ short pl[8][16][40];               // per-wave P bounce
    __shared__ f32x4 red2[8][5][64];
    __shared__ float tl2[16][84];

    const short* qp = Qf + (size_t)qt * 2 * 512 + lane * 8;
    bf16x8 qf0 = *(const bf16x8*)qp;
    bf16x8 qf1 = *(const bf16x8*)(qp + 512);
    bf16x8 ones;
    #pragma unroll
    for (int j = 0; j < 8; ++j) ones[j] = (r == 0) ? (short)0x3F80 : (short)0;

    const float* mlb = Ml + (size_t)batch * SS;
    const float* rlb = Rl + (size_t)batch * SS;
    const short* kfb = Kf + (size_t)batch * 128 * 1024;
    const short* vfb = VF + (size_t)batch * 64 * 4 * 512;

    f32x4 acc[5] = {};

    #pragma unroll 2
    for (int st = 0; st < 8; ++st) {
        const int kt = kbase + st * 32;
        const short* kp = kfb + (size_t)(kt >> 4) * 1024 + lane * 8;
        bf16x8 k00 = *(const bf16x8*)kp;
        bf16x8 k01 = *(const bf16x8*)(kp + 512);
        bf16x8 k10 = *(const bf16x8*)(kp + 1024);
        bf16x8 k11 = *(const bf16x8*)(kp + 1536);
        f32x4 s0 = {}, s1 = {};
        __builtin_amdgcn_s_setprio(1);
        s0 = mfma16(k00, qf0, s0); s0 = mfma16(k01, qf1, s0);
        s1 = mfma16(k10, qf0, s1); s1 = mfma16(k11, qf1, s1);
        __builtin_amdgcn_s_setprio(0);
        f32x4 m0 = *(const f32x4*)(mlb + kt + half * 4);
        f32x4 r0 = *(const f32x4*)(rlb + kt + half * 4);
        f32x4 m1 = *(const f32x4*)(mlb + kt + 16 + half * 4);
        f32x4 r1 = *(const f32x4*)(rlb + kt + 16 + half * 4);
        f32x4 p0, p1;
        #pragma unroll
        for (int ri = 0; ri < 4; ++ri) {
            p0[ri] = exp2f(s0[ri] - m0[ri]) * r0[ri];
            p1[ri] = exp2f(s1[ri] - m1[ri]) * r1[ri];
        }
        uint2 u0, u1;
        u0.x = pk2(p0[0], p0[1]); u0.y = pk2(p0[2], p0[3]);
        u1.x = pk2(p1[0], p1[1]); u1.y = pk2(p1[2], p1[3]);
        *(uint2*)&pl[wave][r][4 * half] = u0;
        *(uint2*)&pl[wave][r][16 + 4 * half] = u1;
        bf16x8 af = *(const bf16x8*)&pl[wave][r][half * 8];
        __builtin_amdgcn_s_setprio(1);
        #pragma unroll
        for (int nn = 0; nn < 4; ++nn) {
            bf16x8 vf = *(const bf16x8*)(vfb + ((size_t)(kt >> 5) * 4 + nn) * 512 + lane * 8);
            acc[nn] = mfma16(af, vf, acc[nn]);
        }
        acc[4] = mfma16(af, ones, acc[4]);
        __builtin_amdgcn_s_setprio(0);
    }

    #pragma unroll
    for (int nn = 0; nn < 5; ++nn) red2[wave][nn][lane] = acc[nn];
    __syncthreads();
    if (wave < 5) {
        int nn = wave;
        f32x4 v = red2[0][nn][lane];
        #pragma unroll
        for (int w = 1; w < 8; ++w) v += red2[w][nn][lane];
        #pragma unroll
        for (int ri = 0; ri < 4; ++ri) tl2[half * 4 + ri][nn * 16 + r] = v[ri];
    }
    __syncthreads();
    if (tid < 320) {
        int ks = tid >> 6;
        int l2 = tid & 63;
        int r2 = l2 & 15, h2 = l2 >> 4;
        bf16x8 o;
        #pragma unroll
        for (int j = 0; j < 8; ++j) {
            float v = tl2[r2][ks * 16 + (h2 & 1) * 8 + j];
            short hi = f2bf(v);
            o[j] = (h2 < 2) ? hi : f2bf(v - bf2f(hi));
        }
        *(bf16x8*)(Tcat2 + (((size_t)qt * 5 + ks) * 64 + l2) * 8) = o;
    }
}

// ---------------------------------------------------------------------------
// K4: GEMM2 — out = Tcat2 (.) Wcat2 over 5 frag-chunks (hi/lo interleave).
// grid 512 flat, block 256. Write-bound.
// ---------------------------------------------------------------------------
__global__ __launch_bounds__(256) void k_gemm2(
    const short* __restrict__ Tcat2, const short* __restrict__ Wcat2,
    float* __restrict__ out)
{
    const int tid = threadIdx.x, wave = tid >> 6, lane = tid & 63;
    const int r = lane & 15, half = lane >> 4;
    const int wm = wave >> 1, wn = wave & 1;
    const int bid = blockIdx.x;
    const int w = (bid & 7) * 64 + (bid >> 3);
    const int qB = (w >> 3) * 128;
    const int vB = (w & 7) * 128;
    const int tA0 = qB / 16 + wm * 4;
    const int vt0 = vB / 16 + wn * 4;

    f32x4 acc[4][4] = {};
    #pragma unroll
    for (int ks = 0; ks < 5; ++ks) {
        bf16x8 a[4], b[4];
        #pragma unroll
        for (int i = 0; i < 4; ++i) {
            a[i] = *(const bf16x8*)(Tcat2 + ((size_t)(tA0 + i) * 5 + ks) * 512 + lane * 8);
            b[i] = *(const bf16x8*)(Wcat2 + ((size_t)(vt0 + i) * 5 + ks) * 512 + lane * 8);
        }
        #pragma unroll
        for (int mi = 0; mi < 4; ++mi)
            #pragma unroll
            for (int ni = 0; ni < 4; ++ni)
                acc[mi][ni] = mfma16(a[mi], b[ni], acc[mi][ni]);
    }

    const int r4 = half * 4;
    #pragma unroll
    for (int mi = 0; mi < 4; ++mi)
        #pragma unroll
        for (int ni = 0; ni < 4; ++ni)
            #pragma unroll
            for (int ri = 0; ri < 4; ++ri)
                out[(size_t)(qB + wm * 64 + mi * 16 + r4 + ri) * EE + vB + wn * 64 + ni * 16 + r] = acc[mi][ni][ri];
}

// ---------------------------------------------------------------------------
extern "C" void kernel_launch(void* const* d_in, const int* in_sizes, int n_in,
                              void* d_out, int out_size, void* d_ws, size_t ws_size,
                              hipStream_t stream) {
    (void)in_sizes; (void)n_in; (void)out_size; (void)ws_size;
    const float* x   = (const float*)d_in[0];
    const float* y   = (const float*)d_in[1];
    const float* Wq  = (const float*)d_in[2];
    const float* bq  = (const float*)d_in[3];
    const float* Wk  = (const float*)d_in[4];
    const float* bk  = (const float*)d_in[5];
    const float* WvR = (const float*)d_in[6];
    const float* bvR = (const float*)d_in[7];
    const float* WvL = (const float*)d_in[8];
    const float* bvL = (const float*)d_in[9];
    float* out = (float*)d_out;

    short* Qf    = (short*)d_ws;                      // 524288 sh
    short* Kf    = Qf    + (size_t)MTOT * DD;         // 524288
    short* VF    = Kf    + (size_t)MTOT * DD;         // 524288
    short* Tcat2 = VF    + (size_t)MTOT * DD;         // 1310720
    short* Wqb   = Tcat2 + (size_t)(MTOT / 16) * 5 * 512;   // 65536
    short* Wkb   = Wqb   + (size_t)DD * EE;
    short* Wvb   = Wkb   + (size_t)DD * EE;
    short* Wcat2 = Wvb   + (size_t)DD * EE;           // 163840
    float* Ml    = (float*)(Wcat2 + (size_t)64 * 5 * 512);  // 8192 f32
    float* Rl    = Ml + MTOT;

    k_prep<<<dim3(176), 256, 0, stream>>>(Wq, Wk, WvR, WvL, bvL, Wqb, Wkb, Wvb, Wcat2);
    k_proj<<<dim3(MTOT / 16, 2), 256, 0, stream>>>(x, y, Wqb, Wkb, Wvb, bq, bk, bvR, Qf, Kf, VF);
    k_stats<<<dim3(SS / 32, NB), 512, 0, stream>>>(Qf, Kf, Ml, Rl);
    k_pvfuse<<<dim3(512), 512, 0, stream>>>(Qf, Kf, VF, Ml, Rl, Tcat2);
    k_gemm2<<<dim3(512), 256, 0, stream>>>(Tcat2, Wcat2, out);
}

// Round 22
// 61.988 us; speedup vs baseline: 1.0492x; 1.0115x over previous
//
#include <hip/hip_runtime.h>
#include <hip/hip_bf16.h>

#define DEV static __device__ __forceinline__
#define AS1 __attribute__((address_space(1)))
#define AS3 __attribute__((address_space(3)))

typedef __attribute__((ext_vector_type(8))) short bf16x8;
typedef __attribute__((ext_vector_type(4))) short bf16x4;
typedef __attribute__((ext_vector_type(4))) float f32x4;

constexpr int NB = 4;        // batches
constexpr int SS = 2048;     // seq
constexpr int EE = 1024;     // embed
constexpr int DD = 64;       // low-rank d
constexpr int MTOT = NB * SS;  // 8192 rows total

// Q is pre-scaled by 1/sqrt(D) * log2(e) so softmax runs in exp2 domain.
#define QSCALE (0.125f * 1.44269504088896340736f)

DEV short f2bf(float f) {
    union { float f; unsigned u; } v; v.f = f;
    unsigned u = v.u;
    u += 0x7FFFu + ((u >> 16) & 1u);   // RNE
    return (short)(u >> 16);
}
DEV float bf2f(short h) {
    union { unsigned u; float f; } v; v.u = ((unsigned)(unsigned short)h) << 16;
    return v.f;
}
// packed bf16 pair via HW instruction (RNE, same as f2bf)
DEV unsigned pk2(float a, float b) {
    unsigned r;
    asm("v_cvt_pk_bf16_f32 %0, %1, %2" : "=v"(r) : "v"(a), "v"(b));
    return r;
}

DEV f32x4 mfma16(bf16x8 a, bf16x8 b, f32x4 c) {
    return __builtin_amdgcn_mfma_f32_16x16x32_bf16(a, b, c, 0, 0, 0);
}

DEV float redmax16(float v) {
    v = fmaxf(v, __shfl_xor(v, 1)); v = fmaxf(v, __shfl_xor(v, 2));
    v = fmaxf(v, __shfl_xor(v, 4)); v = fmaxf(v, __shfl_xor(v, 8));
    return v;
}
DEV float redsum16(float v) {
    v += __shfl_xor(v, 1); v += __shfl_xor(v, 2);
    v += __shfl_xor(v, 4); v += __shfl_xor(v, 8);
    return v;
}

// Frag layouts (all bf16, chunk = 64 lanes x 8 shorts = 1KB):
//  Qf/Kf  : [tile = globalrow/16][h2 = d/32]
//  VF     : [batch][c = k/32][n = d/16]
//  Tcat2  : [qtile][ks 0..4]  hi/lo slot map
//  Wcat2  : [vtile][ks 0..4]  (col 64 = bvL, 65.. = 0)
//  Wqb/Wkb/Wvb: sigma-PERMUTED frags matching k_proj's contiguous A-load.
//  Cl     : per-k softmax constant C = M + log2(L); p = exp2(s - C).

// ---------------------------------------------------------------------------
// K0: fused weight prep: sigma-permuted frag-ordered Wq/Wk/Wv + Wcat2.
// grid 176, block 256.
// ---------------------------------------------------------------------------
__global__ __launch_bounds__(256) void k_prep(
    const float* __restrict__ Wq, const float* __restrict__ Wk,
    const float* __restrict__ Wv, const float* __restrict__ WvL,
    const float* __restrict__ bvL,
    short* __restrict__ Wqb, short* __restrict__ Wkb, short* __restrict__ Wvb,
    short* __restrict__ Wcat2)
{
    int g = blockIdx.x * 256 + threadIdx.x;
    if (g < 24576) {
        int mat = g >> 13;
        int c = g & 8191;
        int lane = c & 63;
        int fn = (c >> 6) & 3;
        int it = (c >> 8) & 7;
        int kq4 = c >> 11;
        int r = lane & 15, half = lane >> 4;
        int row = fn * 16 + r;
        int col = kq4 * 256 + it * 32 + half * 4;    // sigma
        const float* W = (mat == 0) ? Wq : ((mat == 1) ? Wk : Wv);
        short* O = (mat == 0) ? Wqb : ((mat == 1) ? Wkb : Wvb);
        float s = (mat == 0) ? QSCALE : 1.0f;
        const float* Wp = W + (size_t)row * EE + col;
        float4 u = *(const float4*)(Wp);
        float4 v = *(const float4*)(Wp + 16);
        bf16x8 o;
        unsigned* ou = (unsigned*)&o;
        ou[0] = pk2(u.x * s, u.y * s);
        ou[1] = pk2(u.z * s, u.w * s);
        ou[2] = pk2(v.x * s, v.y * s);
        ou[3] = pk2(v.z * s, v.w * s);
        *(bf16x8*)(O + (size_t)c * 8) = o;
    } else {
        int i2 = g - 24576;                  // 0..20479
        int lane = i2 & 63;
        int ks = (i2 >> 6) % 5;
        int vt = i2 / 320;
        int r = lane & 15, h = lane >> 4;
        int v = vt * 16 + r;
        bf16x8 o;
        #pragma unroll
        for (int j = 0; j < 8; ++j) {
            int c = ks * 16 + (h & 1) * 8 + j;
            float val = (c < 64) ? WvL[(size_t)v * DD + c] : ((c == 64) ? bvL[v] : 0.f);
            o[j] = f2bf(val);
        }
        *(bf16x8*)(Wcat2 + ((size_t)(vt * 5 + ks) * 64 + lane) * 8) = o;
    }
}

// ---------------------------------------------------------------------------
// K1 (R19 version — best measured): projections, split-K, sigma-permuted W;
// W-frags double-buffered one iteration ahead; A fully prefetched.
// grid (512, 2), block 256.
// ---------------------------------------------------------------------------
__global__ __launch_bounds__(256) void k_proj(
    const float* __restrict__ x, const float* __restrict__ y,
    const short* __restrict__ Wqb, const short* __restrict__ Wkb,
    const short* __restrict__ Wvb,
    const float* __restrict__ bq, const float* __restrict__ bk,
    const float* __restrict__ bv,
    short* __restrict__ Qf, short* __restrict__ Kf, short* __restrict__ VF)
{
    const int tid = threadIdx.x, wave = tid >> 6, lane = tid & 63;
    const int r = lane & 15, half = lane >> 4;
    const int rb = blockIdx.x * 16;
    const bool isQ = (blockIdx.y == 0);
    const float* src = isQ ? x : y;
    const short* wA = isQ ? Wqb : Wkb;
    const int kq = wave * 256;

    __shared__ f32x4 red[4][8][64];

    f32x4 accA[4] = {}, accB[4] = {};
    const float* arow = src + (size_t)(rb + r) * EE + kq + half * 4;  // sigma
    const short* wbase = wA + (size_t)wave * 16384 + lane * 8;
    const short* vbase = Wvb + (size_t)wave * 16384 + lane * 8;

    float4 af0[8], af1[8];
    #pragma unroll
    for (int it = 0; it < 8; ++it) {
        af0[it] = *(const float4*)(arow + it * 32);        // cols 4h+0..3
        af1[it] = *(const float4*)(arow + it * 32 + 16);   // cols 16+4h+0..3
    }

    // W double-buffer: preload it=0
    bf16x8 bwc[4], bvc[4], bwn[4], bvn[4];
    #pragma unroll
    for (int n = 0; n < 4; ++n) bwc[n] = *(const bf16x8*)(wbase + n * 512);
    if (!isQ) {
        #pragma unroll
        for (int n = 0; n < 4; ++n) bvc[n] = *(const bf16x8*)(vbase + n * 512);
    }

    #pragma unroll
    for (int it = 0; it < 8; ++it) {
        if (it < 7) {
            #pragma unroll
            for (int n = 0; n < 4; ++n)
                bwn[n] = *(const bf16x8*)(wbase + ((it + 1) * 4 + n) * 512);
            if (!isQ) {
                #pragma unroll
                for (int n = 0; n < 4; ++n)
                    bvn[n] = *(const bf16x8*)(vbase + ((it + 1) * 4 + n) * 512);
            }
        }
        bf16x8 a;
        unsigned* au = (unsigned*)&a;
        au[0] = pk2(af0[it].x, af0[it].y);
        au[1] = pk2(af0[it].z, af0[it].w);
        au[2] = pk2(af1[it].x, af1[it].y);
        au[3] = pk2(af1[it].z, af1[it].w);
        #pragma unroll
        for (int n = 0; n < 4; ++n)
            accA[n] = mfma16(a, bwc[n], accA[n]);
        if (!isQ) {
            #pragma unroll
            for (int n = 0; n < 4; ++n)
                accB[n] = mfma16(a, bvc[n], accB[n]);
        }
        #pragma unroll
        for (int n = 0; n < 4; ++n) bwc[n] = bwn[n];
        if (!isQ) {
            #pragma unroll
            for (int n = 0; n < 4; ++n) bvc[n] = bvn[n];
        }
    }

    #pragma unroll
    for (int n = 0; n < 4; ++n) red[wave][n][lane] = accA[n];
    if (!isQ) {
        #pragma unroll
        for (int n = 0; n < 4; ++n) red[wave][4 + n][lane] = accB[n];
    }
    __syncthreads();

    const int n = wave;
    const int col = n * 16 + r;
    f32x4 s = red[0][n][lane];
    #pragma unroll
    for (int w = 1; w < 4; ++w) s += red[w][n][lane];
    float biasA = isQ ? (bq[col] * QSCALE) : bk[col];
    f32x4 t = {};
    float biasB = 0.f;
    if (!isQ) {
        t = red[0][4 + n][lane];
        #pragma unroll
        for (int w = 1; w < 4; ++w) t += red[w][4 + n][lane];
        biasB = bv[col];
    }
    __syncthreads();                       // red consumed; alias as f32 tiles
    float* tlA = (float*)&red[0][0][0];    // [16][68]
    float* tlB = tlA + 16 * 68;            // [16][68]
    #pragma unroll
    for (int ri = 0; ri < 4; ++ri)
        tlA[(half * 4 + ri) * 68 + col] = s[ri] + biasA;
    if (!isQ) {
        #pragma unroll
        for (int ri = 0; ri < 4; ++ri)
            tlB[(half * 4 + ri) * 68 + col] = t[ri] + biasB;
    }
    __syncthreads();
    if (tid < 128) {
        int h2 = tid >> 6, l2 = tid & 63, r2 = l2 & 15, hh = l2 >> 4;
        const float* base = tlA + r2 * 68 + h2 * 32 + hh * 8;
        bf16x8 o;
        unsigned* ou = (unsigned*)&o;
        #pragma unroll
        for (int jj = 0; jj < 4; ++jj)
            ou[jj] = pk2(base[2 * jj], base[2 * jj + 1]);
        short* dst = (isQ ? Qf : Kf) + ((size_t)blockIdx.x * 2 + h2) * 512 + l2 * 8;
        *(bf16x8*)dst = o;
    } else if (!isQ) {
        int idx = tid - 128;                 // 0..127
        int nn = idx >> 5, sub = idx & 31;
        int r2 = sub & 15, su = sub >> 4;    // su in {0,1}
        int hbase = (rb & 16) ? 2 : 0;
        int lane2 = ((hbase + su) << 4) | r2;
        const float* base = tlB + (size_t)su * 8 * 68 + nn * 16 + r2;
        bf16x8 o;
        unsigned* ou = (unsigned*)&o;
        #pragma unroll
        for (int jj = 0; jj < 4; ++jj)
            ou[jj] = pk2(base[(2 * jj) * 68], base[(2 * jj + 1) * 68]);
        int batch = rb >> 11;
        int cg2 = (rb & 2047) >> 5;
        *(bf16x8*)(VF + (((size_t)batch * 64 + cg2) * 4 + nn) * 512 + lane2 * 8) = o;
    }
}

// ---------------------------------------------------------------------------
// K2 v3: column-softmax STATS, 32 k-cols per block; emits the FOLDED
// constant C[k] = M[k] + log2(L[k]) so pvfuse computes p = exp2(s - C)
// (no per-element multiply, single stats load). grid (64, NB), block 512.
// ---------------------------------------------------------------------------
__global__ __launch_bounds__(512) void k_stats(
    const short* __restrict__ Qf, const short* __restrict__ Kf,
    float* __restrict__ Cl)
{
    const int tid = threadIdx.x, wave = tid >> 6, lane = tid & 63;
    const int r = lane & 15, half = lane >> 4;
    const int batch = blockIdx.y;
    const int kb = blockIdx.x * 32;

    __shared__ float smax[8][32], ssum[8][32];

    const short* kfp = Kf + ((size_t)(batch * 128 + (kb >> 4)) * 2) * 512 + lane * 8;
    bf16x8 kf0 = *(const bf16x8*)kfp;
    bf16x8 kf1 = *(const bf16x8*)(kfp + 512);
    bf16x8 kf2 = *(const bf16x8*)(kfp + 1024);
    bf16x8 kf3 = *(const bf16x8*)(kfp + 1536);

    const int qt0 = batch * 128 + wave * 16;
    f32x4 sa[16], sb[16];
    #pragma unroll
    for (int t = 0; t < 16; ++t) {
        const short* qp = Qf + ((size_t)(qt0 + t) * 2) * 512 + lane * 8;
        bf16x8 a0 = *(const bf16x8*)qp;
        bf16x8 a1 = *(const bf16x8*)(qp + 512);
        f32x4 ca = {}, cb = {};
        ca = mfma16(kf0, a0, ca);
        ca = mfma16(kf1, a1, ca);
        cb = mfma16(kf2, a0, cb);
        cb = mfma16(kf3, a1, cb);
        sa[t] = ca;
        sb[t] = cb;
    }
    f32x4 m4a = sa[0], m4b = sb[0];
    #pragma unroll
    for (int t = 1; t < 16; ++t) {
        #pragma unroll
        for (int ri = 0; ri < 4; ++ri) {
            m4a[ri] = fmaxf(m4a[ri], sa[t][ri]);
            m4b[ri] = fmaxf(m4b[ri], sb[t][ri]);
        }
    }
    #pragma unroll
    for (int ri = 0; ri < 4; ++ri) {
        m4a[ri] = redmax16(m4a[ri]);
        m4b[ri] = redmax16(m4b[ri]);
    }
    if (r == 0) {
        #pragma unroll
        for (int ri = 0; ri < 4; ++ri) {
            smax[wave][half * 4 + ri] = m4a[ri];
            smax[wave][16 + half * 4 + ri] = m4b[ri];
        }
    }
    __syncthreads();
    f32x4 Ma, Mb;
    #pragma unroll
    for (int ri = 0; ri < 4; ++ri) {
        float va = smax[0][half * 4 + ri];
        float vb = smax[0][16 + half * 4 + ri];
        #pragma unroll
        for (int w = 1; w < 8; ++w) {
            va = fmaxf(va, smax[w][half * 4 + ri]);
            vb = fmaxf(vb, smax[w][16 + half * 4 + ri]);
        }
        Ma[ri] = va; Mb[ri] = vb;
    }
    f32x4 l4a = {}, l4b = {};
    #pragma unroll
    for (int t = 0; t < 16; ++t) {
        #pragma unroll
        for (int ri = 0; ri < 4; ++ri) {
            l4a[ri] += exp2f(sa[t][ri] - Ma[ri]);
            l4b[ri] += exp2f(sb[t][ri] - Mb[ri]);
        }
    }
    #pragma unroll
    for (int ri = 0; ri < 4; ++ri) {
        l4a[ri] = redsum16(l4a[ri]);
        l4b[ri] = redsum16(l4b[ri]);
    }
    if (r == 0) {
        #pragma unroll
        for (int ri = 0; ri < 4; ++ri) {
            ssum[wave][half * 4 + ri] = l4a[ri];
            ssum[wave][16 + half * 4 + ri] = l4b[ri];
        }
    }
    __syncthreads();
    if (wave == 0 && r == 0) {
        f32x4 Ca, Cb;
        #pragma unroll
        for (int ri = 0; ri < 4; ++ri) {
            float va = 0.f, vb = 0.f;
            #pragma unroll
            for (int w = 0; w < 8; ++w) {
                va += ssum[w][half * 4 + ri];
                vb += ssum[w][16 + half * 4 + ri];
            }
            Ca[ri] = Ma[ri] + __log2f(va);
            Cb[ri] = Mb[ri] + __log2f(vb);
        }
        *(f32x4*)(Cl + (size_t)batch * SS + kb + half * 4) = Ca;
        *(f32x4*)(Cl + (size_t)batch * SS + kb + 16 + half * 4) = Cb;
    }
}

// ---------------------------------------------------------------------------
// K3: fused PV, flash-style — p = exp2(s - C) (folded stats: no mul, one
// load). Block = 16 q-rows; 8 waves k-split 256; setprio around MFMA.
// grid 512 (XCD-chunked), block 512.
// ---------------------------------------------------------------------------
__global__ __launch_bounds__(512) void k_pvfuse(
    const short* __restrict__ Qf, const short* __restrict__ Kf,
    const short* __restrict__ VF,
    const float* __restrict__ Cl,
    short* __restrict__ Tcat2)
{
    const int tid = threadIdx.x, wave = tid >> 6, lane = tid & 63;
    const int r = lane & 15, half = lane >> 4;
    const int bid = blockIdx.x;
    const int qt = (bid & 7) * 64 + (bid >> 3);   // XCD-chunked; 0..511
    const int batch = qt >> 7;
    const int kbase = wave * 256;

    __shared__ short pl[8][16][40];               // per-wave P bounce
    __shared__ f32x4 red2[8][5][64];
    __shared__ float tl2[16][84];

    const short* qp = Qf + (size_t)qt * 2 * 512 + lane * 8;
    bf16x8 qf0 = *(const bf16x8*)qp;
    bf16x8 qf1 = *(const bf16x8*)(qp + 512);
    bf16x8 ones;
    #pragma unroll
    for (int j = 0; j < 8; ++j) ones[j] = (r == 0) ? (short)0x3F80 : (short)0;

    const float* clb = Cl + (size_t)batch * SS;
    const short* kfb = Kf + (size_t)batch * 128 * 1024;
    const short* vfb = VF + (size_t)batch * 64 * 4 * 512;

    f32x4 acc[5] = {};

    #pragma unroll 2
    for (int st = 0; st < 8; ++st) {
        const int kt = kbase + st * 32;
        const short* kp = kfb + (size_t)(kt >> 4) * 1024 + lane * 8;
        bf16x8 k00 = *(const bf16x8*)kp;
        bf16x8 k01 = *(const bf16x8*)(kp + 512);
        bf16x8 k10 = *(const bf16x8*)(kp + 1024);
        bf16x8 k11 = *(const bf16x8*)(kp + 1536);
        f32x4 s0 = {}, s1 = {};
        __builtin_amdgcn_s_setprio(1);
        s0 = mfma16(k00, qf0, s0); s0 = mfma16(k01, qf1, s0);
        s1 = mfma16(k10, qf0, s1); s1 = mfma16(k11, qf1, s1);
        __builtin_amdgcn_s_setprio(0);
        f32x4 c0 = *(const f32x4*)(clb + kt + half * 4);
        f32x4 c1 = *(const f32x4*)(clb + kt + 16 + half * 4);
        f32x4 p0, p1;
        #pragma unroll
        for (int ri = 0; ri < 4; ++ri) {
            p0[ri] = exp2f(s0[ri] - c0[ri]);
            p1[ri] = exp2f(s1[ri] - c1[ri]);
        }
        uint2 u0, u1;
        u0.x = pk2(p0[0], p0[1]); u0.y = pk2(p0[2], p0[3]);
        u1.x = pk2(p1[0], p1[1]); u1.y = pk2(p1[2], p1[3]);
        *(uint2*)&pl[wave][r][4 * half] = u0;
        *(uint2*)&pl[wave][r][16 + 4 * half] = u1;
        bf16x8 af = *(const bf16x8*)&pl[wave][r][half * 8];
        __builtin_amdgcn_s_setprio(1);
        #pragma unroll
        for (int nn = 0; nn < 4; ++nn) {
            bf16x8 vf = *(const bf16x8*)(vfb + ((size_t)(kt >> 5) * 4 + nn) * 512 + lane * 8);
            acc[nn] = mfma16(af, vf, acc[nn]);
        }
        acc[4] = mfma16(af, ones, acc[4]);
        __builtin_amdgcn_s_setprio(0);
    }

    #pragma unroll
    for (int nn = 0; nn < 5; ++nn) red2[wave][nn][lane] = acc[nn];
    __syncthreads();
    if (wave < 5) {
        int nn = wave;
        f32x4 v = red2[0][nn][lane];
        #pragma unroll
        for (int w = 1; w < 8; ++w) v += red2[w][nn][lane];
        #pragma unroll
        for (int ri = 0; ri < 4; ++ri) tl2[half * 4 + ri][nn * 16 + r] = v[ri];
    }
    __syncthreads();
    if (tid < 320) {
        int ks = tid >> 6;
        int l2 = tid & 63;
        int r2 = l2 & 15, h2 = l2 >> 4;
        bf16x8 o;
        #pragma unroll
        for (int j = 0; j < 8; ++j) {
            float v = tl2[r2][ks * 16 + (h2 & 1) * 8 + j];
            short hi = f2bf(v);
            o[j] = (h2 < 2) ? hi : f2bf(v - bf2f(hi));
        }
        *(bf16x8*)(Tcat2 + (((size_t)qt * 5 + ks) * 64 + l2) * 8) = o;
    }
}

// ---------------------------------------------------------------------------
// K4: GEMM2 — out = Tcat2 (.) Wcat2 over 5 frag-chunks (hi/lo interleave).
// grid 512 flat, block 256. Write-bound.
// ---------------------------------------------------------------------------
__global__ __launch_bounds__(256) void k_gemm2(
    const short* __restrict__ Tcat2, const short* __restrict__ Wcat2,
    float* __restrict__ out)
{
    const int tid = threadIdx.x, wave = tid >> 6, lane = tid & 63;
    const int r = lane & 15, half = lane >> 4;
    const int wm = wave >> 1, wn = wave & 1;
    const int bid = blockIdx.x;
    const int w = (bid & 7) * 64 + (bid >> 3);
    const int qB = (w >> 3) * 128;
    const int vB = (w & 7) * 128;
    const int tA0 = qB / 16 + wm * 4;
    const int vt0 = vB / 16 + wn * 4;

    f32x4 acc[4][4] = {};
    #pragma unroll
    for (int ks = 0; ks < 5; ++ks) {
        bf16x8 a[4], b[4];
        #pragma unroll
        for (int i = 0; i < 4; ++i) {
            a[i] = *(const bf16x8*)(Tcat2 + ((size_t)(tA0 + i) * 5 + ks) * 512 + lane * 8);
            b[i] = *(const bf16x8*)(Wcat2 + ((size_t)(vt0 + i) * 5 + ks) * 512 + lane * 8);
        }
        #pragma unroll
        for (int mi = 0; mi < 4; ++mi)
            #pragma unroll
            for (int ni = 0; ni < 4; ++ni)
                acc[mi][ni] = mfma16(a[mi], b[ni], acc[mi][ni]);
    }

    const int r4 = half * 4;
    #pragma unroll
    for (int mi = 0; mi < 4; ++mi)
        #pragma unroll
        for (int ni = 0; ni < 4; ++ni)
            #pragma unroll
            for (int ri = 0; ri < 4; ++ri)
                out[(size_t)(qB + wm * 64 + mi * 16 + r4 + ri) * EE + vB + wn * 64 + ni * 16 + r] = acc[mi][ni][ri];
}

// ---------------------------------------------------------------------------
extern "C" void kernel_launch(void* const* d_in, const int* in_sizes, int n_in,
                              void* d_out, int out_size, void* d_ws, size_t ws_size,
                              hipStream_t stream) {
    (void)in_sizes; (void)n_in; (void)out_size; (void)ws_size;
    const float* x   = (const float*)d_in[0];
    const float* y   = (const float*)d_in[1];
    const float* Wq  = (const float*)d_in[2];
    const float* bq  = (const float*)d_in[3];
    const float* Wk  = (const float*)d_in[4];
    const float* bk  = (const float*)d_in[5];
    const float* WvR = (const float*)d_in[6];
    const float* bvR = (const float*)d_in[7];
    const float* WvL = (const float*)d_in[8];
    const float* bvL = (const float*)d_in[9];
    float* out = (float*)d_out;

    short* Qf    = (short*)d_ws;                      // 524288 sh
    short* Kf    = Qf    + (size_t)MTOT * DD;         // 524288
    short* VF    = Kf    + (size_t)MTOT * DD;         // 524288
    short* Tcat2 = VF    + (size_t)MTOT * DD;         // 1310720
    short* Wqb   = Tcat2 + (size_t)(MTOT / 16) * 5 * 512;   // 65536
    short* Wkb   = Wqb   + (size_t)DD * EE;
    short* Wvb   = Wkb   + (size_t)DD * EE;
    short* Wcat2 = Wvb   + (size_t)DD * EE;           // 163840
    float* Cl    = (float*)(Wcat2 + (size_t)64 * 5 * 512);  // 8192 f32

    k_prep<<<dim3(176), 256, 0, stream>>>(Wq, Wk, WvR, WvL, bvL, Wqb, Wkb, Wvb, Wcat2);
    k_proj<<<dim3(MTOT / 16, 2), 256, 0, stream>>>(x, y, Wqb, Wkb, Wvb, bq, bk, bvR, Qf, Kf, VF);
    k_stats<<<dim3(SS / 32, NB), 512, 0, stream>>>(Qf, Kf, Cl);
    k_pvfuse<<<dim3(512), 512, 0, stream>>>(Qf, Kf, VF, Cl, Tcat2);
    k_gemm2<<<dim3(512), 256, 0, stream>>>(Tcat2, Wcat2, out);
}